// Round 4
// baseline (320.051 us; speedup 1.0000x reference)
//
#include <hip/hip_runtime.h>

// PrimalCosAttention fused kernel. R4: persistent blocks + software pipeline.
// B=4 H=12 N=4096 D=64 E=32. Grid = 48 bh * 16 = 768 blocks (3/CU, fully
// resident). Each block: stage weights once, hoist all MFMA B-fragments to
// registers, then loop over 4 consecutive 64-row n-tiles with register
// prefetch of the next tile's Q/K overlapping the current tile's compute.

namespace {
constexpr int Hh = 12;
constexpr int Nn = 4096;
constexpr int TPB = 4;                    // tiles per block
// output offsets in floats
constexpr int O_ATTN = 0;
constexpr int O_ES   = 12582912;
constexpr int O_RS   = 18874368;
constexpr int O_WE   = 25165824;
constexpr int O_WR   = 25190400;
constexpr int O_Q    = 25214976;
constexpr int O_K    = 37797888;
constexpr int O_LAM  = 50380800;
}

typedef float  v4f  __attribute__((ext_vector_type(4)));
typedef __bf16 v8bf __attribute__((ext_vector_type(8)));

// fp32 -> bf16 round-to-nearest-even
__device__ __forceinline__ unsigned short f2b(float f) {
    unsigned int x = __float_as_uint(f);
    x += 0x7fffu + ((x >> 16) & 1u);
    return (unsigned short)(x >> 16);
}

// Swizzled index (ushorts) into [rows][64] bf16: 16B chunk ^= (row&7).
__device__ __forceinline__ int swz(int row, int k) {
    return row * 64 + (((k >> 3) ^ (row & 7)) << 3) + (k & 7);
}

__global__ __launch_bounds__(256, 3)
void pca_fused(const float* __restrict__ Q, const float* __restrict__ Kp,
               const float* __restrict__ we, const float* __restrict__ wr,
               const float* __restrict__ mask, const float* __restrict__ W,
               const float* __restrict__ bias, const float* __restrict__ Lam,
               float* __restrict__ out)
{
    // 32 KiB LDS
    __shared__ __align__(16) unsigned short Qs[4096];   // Qn [64][64]; reused as S
    __shared__ __align__(16) unsigned short Ks[4096];   // Kn [64][64]
    __shared__ __align__(16) unsigned short WEs[2048];  // we_h^T [e 32][d 64]
    __shared__ __align__(16) unsigned short WRs[2048];  // wr_h^T [e 32][d 64]
    __shared__ __align__(16) unsigned short Ws_[4096];  // W      [d 64][e 64]

    const int tid = threadIdx.x;
    const int bh  = blockIdx.x >> 4;        // 0..47 (b*12+h)
    const int tb  = blockIdx.x & 15;        // tile group; tiles tb*4 .. tb*4+3
    const int h   = bh % Hh;
    const int bb  = bh / Hh;

    // ---- passthrough outputs (we0 / wr0 / Lambda) ----
    if (blockIdx.x < 49) {
        int i4 = blockIdx.x * 256 + tid;
        if (i4 < 6144) {
            ((float4*)(out + O_WE))[i4] = ((const float4*)we)[i4];
        } else if (i4 < 12288) {
            ((float4*)(out + O_WR))[i4 - 6144] = ((const float4*)wr)[i4 - 6144];
        } else if (i4 < 12384) {
            ((float4*)(out + O_LAM))[i4 - 12288] = ((const float4*)Lam)[i4 - 12288];
        }
    }

    // ---- stage weights to bf16 LDS (once per block) ----
    {
        const float* weh = we + h * 2048;   // [d 64][e 32]
        const float* wrh = wr + h * 2048;
#pragma unroll
        for (int j = 0; j < 8; ++j) {
            int i = tid + 256 * j;
            int d = i >> 5, e = i & 31;
            WEs[swz(e, d)] = f2b(weh[i]);
            WRs[swz(e, d)] = f2b(wrh[i]);
        }
#pragma unroll
        for (int j = 0; j < 16; ++j) {
            int i = tid + 256 * j;          // W is [d 64][e2 64]
            int d = i >> 6, e = i & 63;
            Ws_[swz(d, e)] = f2b(W[i]);
        }
    }

    const int rr = tid >> 4;                // row-in-group 0..15
    const int c4 = (tid & 15) << 2;         // col chunk

    // ---- prefetch tile 0 ----
    float4 pq[4], pk[4];
    {
        int g0 = (bh * Nn + (tb << 8)) * 64 + rr * 64 + c4;
#pragma unroll
        for (int p = 0; p < 4; ++p) {
            pq[p] = *(const float4*)(Q  + g0 + p * 1024);
            pk[p] = *(const float4*)(Kp + g0 + p * 1024);
        }
    }
    __syncthreads();    // weights visible to all waves

    const int w    = tid >> 6;        // wave id; owns rows [16w,16w+16)
    const int lane = tid & 63;
    const int quad = lane >> 4;
    const int n16  = lane & 15;
    const int m    = w * 16 + n16;

    auto ldf = [&](const unsigned short* b, int row, int kb) -> v8bf {
        return *(const v8bf*)(b + row * 64 + ((((kb << 2) + quad) ^ (row & 7)) << 3));
    };

    // ---- hoist all B-operand fragments + bias to registers ----
    v8bf wE[4], wR[4], wW[8];
#pragma unroll
    for (int nt = 0; nt < 2; ++nt) {
        wE[nt * 2 + 0] = ldf(WEs, nt * 16 + n16, 0);
        wE[nt * 2 + 1] = ldf(WEs, nt * 16 + n16, 1);
        wR[nt * 2 + 0] = ldf(WRs, nt * 16 + n16, 0);
        wR[nt * 2 + 1] = ldf(WRs, nt * 16 + n16, 1);
    }
#pragma unroll
    for (int nt = 0; nt < 4; ++nt) {
        wW[nt * 2 + 0] = ldf(Ws_, nt * 16 + n16, 0);
        wW[nt * 2 + 1] = ldf(Ws_, nt * 16 + n16, 1);
    }
    float bv4[4];
#pragma unroll
    for (int nt = 0; nt < 4; ++nt) bv4[nt] = bias[nt * 16 + n16];

    for (int it = 0; it < TPB; ++it) {
        const int n0 = ((tb << 2) + it) << 6;
        const int gt = (bh * Nn + n0) * 64;           // tile base (elems)

        // ---- phase 1: normalize prefetched Q/K, write q/k, stage bf16 LDS ----
#pragma unroll
        for (int p = 0; p < 4; ++p) {
            int r = p * 16 + rr;
            int g = gt + r * 64 + c4;
            float4 q4 = pq[p], k4 = pk[p];
            float sq = q4.x*q4.x + q4.y*q4.y + q4.z*q4.z + q4.w*q4.w;
            float sk = k4.x*k4.x + k4.y*k4.y + k4.z*k4.z + k4.w*k4.w;
#pragma unroll
            for (int mm = 1; mm < 16; mm <<= 1) {
                sq += __shfl_xor(sq, mm, 64);
                sk += __shfl_xor(sk, mm, 64);
            }
            float iq = 1.0f / fmaxf(sqrtf(sq), 1e-12f);
            float ik = 1.0f / fmaxf(sqrtf(sk), 1e-12f);
            q4.x *= iq; q4.y *= iq; q4.z *= iq; q4.w *= iq;
            k4.x *= ik; k4.y *= ik; k4.z *= ik; k4.w *= ik;
            *(float4*)(out + O_Q + g) = q4;
            *(float4*)(out + O_K + g) = k4;
            int a = swz(r, c4);
            *(ushort4*)(Qs + a) = make_ushort4(f2b(q4.x), f2b(q4.y), f2b(q4.z), f2b(q4.w));
            *(ushort4*)(Ks + a) = make_ushort4(f2b(k4.x), f2b(k4.y), f2b(k4.z), f2b(k4.w));
        }
        // ---- prefetch next tile (overlaps this tile's GEMMs/stores) ----
        if (it + 1 < TPB) {
            int gn = gt + 64 * 64 + rr * 64 + c4;     // next tile base
#pragma unroll
            for (int p = 0; p < 4; ++p) {
                pq[p] = *(const float4*)(Q  + gn + p * 1024);
                pk[p] = *(const float4*)(Kp + gn + p * 1024);
            }
        }
        __syncthreads();                              // barrier A: Qs/Ks ready

        // ---- GEMM1: escore = Qn @ we_h, rscore = Kn @ wr_h ----
        v8bf aq0 = ldf(Qs, m, 0), aq1 = ldf(Qs, m, 1);
        v8bf ak0 = ldf(Ks, m, 0), ak1 = ldf(Ks, m, 1);
        v4f accE[2], accR[2];
#pragma unroll
        for (int nt = 0; nt < 2; ++nt) {
            accE[nt] = (v4f){0.f, 0.f, 0.f, 0.f};
            accR[nt] = (v4f){0.f, 0.f, 0.f, 0.f};
            accE[nt] = __builtin_amdgcn_mfma_f32_16x16x32_bf16(aq0, wE[nt*2+0], accE[nt], 0, 0, 0);
            accE[nt] = __builtin_amdgcn_mfma_f32_16x16x32_bf16(aq1, wE[nt*2+1], accE[nt], 0, 0, 0);
            accR[nt] = __builtin_amdgcn_mfma_f32_16x16x32_bf16(ak0, wR[nt*2+0], accR[nt], 0, 0, 0);
            accR[nt] = __builtin_amdgcn_mfma_f32_16x16x32_bf16(ak1, wR[nt*2+1], accR[nt], 0, 0, 0);
        }

        // ---- write escore/rscore fp32; stage S bf16 into Qs (wave-private) ----
#pragma unroll
        for (int nt = 0; nt < 2; ++nt) {
#pragma unroll
            for (int i = 0; i < 4; ++i) {
                int r = w * 16 + quad * 4 + i;
                int n = n0 + r;
                out[O_ES + (bh * Nn + n) * 32 + nt * 16 + n16] = accE[nt][i];
                out[O_RS + (bh * Nn + n) * 32 + nt * 16 + n16] = accR[nt][i];
                Qs[swz(r, nt * 16 + n16)]      = f2b(accE[nt][i]);
                Qs[swz(r, 32 + nt * 16 + n16)] = f2b(accR[nt][i]);
            }
        }

        // ---- GEMM2: attn = S @ W^T + b  (slab-private, no barrier) ----
        v8bf as0 = ldf(Qs, m, 0), as1 = ldf(Qs, m, 1);
        v4f accD[4];
#pragma unroll
        for (int nt = 0; nt < 4; ++nt) {
            float bv = bv4[nt];
            accD[nt] = (v4f){bv, bv, bv, bv};
            accD[nt] = __builtin_amdgcn_mfma_f32_16x16x32_bf16(as0, wW[nt*2+0], accD[nt], 0, 0, 0);
            accD[nt] = __builtin_amdgcn_mfma_f32_16x16x32_bf16(as1, wW[nt*2+1], accD[nt], 0, 0, 0);
        }
        __syncthreads();                  // barrier B: all LDS reads done

        float mv[4];
#pragma unroll
        for (int i = 0; i < 4; ++i) mv[i] = mask[bb * Nn + n0 + w * 16 + quad * 4 + i];
#pragma unroll
        for (int nt = 0; nt < 4; ++nt) {
#pragma unroll
            for (int i = 0; i < 4; ++i) {
                int n = n0 + w * 16 + quad * 4 + i;
                out[O_ATTN + (bh * Nn + n) * 64 + nt * 16 + n16] = accD[nt][i] * mv[i];
            }
        }
    }
}

extern "C" void kernel_launch(void* const* d_in, const int* in_sizes, int n_in,
                              void* d_out, int out_size, void* d_ws, size_t ws_size,
                              hipStream_t stream) {
    const float* Q    = (const float*)d_in[0];
    const float* Kp   = (const float*)d_in[1];
    const float* we   = (const float*)d_in[2];
    const float* wr   = (const float*)d_in[3];
    const float* mask = (const float*)d_in[4];
    const float* W    = (const float*)d_in[5];
    const float* bias = (const float*)d_in[6];
    const float* Lam  = (const float*)d_in[7];
    float* out = (float*)d_out;

    pca_fused<<<dim3(48 * 16), dim3(256), 0, stream>>>(Q, Kp, we, wr, mask, W, bias, Lam, out);
}